// Round 1
// baseline (2749.594 us; speedup 1.0000x reference)
//
#include <hip/hip_runtime.h>
#include <hip/hip_bf16.h>
#include <stdint.h>

#define TT 4096
#define HH 4096
#define FF 14336

typedef __attribute__((ext_vector_type(8))) short bf16x8;
typedef __attribute__((ext_vector_type(4))) float f32x4;

__device__ __forceinline__ unsigned short f32_to_bf16(float f) {
    union { float f; unsigned int u; } v; v.f = f;
    unsigned int r = v.u + 0x7FFFu + ((v.u >> 16) & 1u);  // RNE
    return (unsigned short)(r >> 16);
}

#define GLOAD16(g, l)                                                          \
    __builtin_amdgcn_global_load_lds(                                          \
        (const __attribute__((address_space(1))) void*)(g),                    \
        (__attribute__((address_space(3))) void*)(l), 16, 0, 0)

// ---------------- convert fp32 -> bf16, same layout ----------------
__global__ void cvt_lin(const float* __restrict__ in,
                        unsigned short* __restrict__ out, long n4) {
    long stride = (long)gridDim.x * blockDim.x;
    for (long i = (long)blockIdx.x * blockDim.x + threadIdx.x; i < n4; i += stride) {
        float4 v = *(const float4*)(in + i * 4);
        ushort4 o;
        o.x = f32_to_bf16(v.x); o.y = f32_to_bf16(v.y);
        o.z = f32_to_bf16(v.z); o.w = f32_to_bf16(v.w);
        *(ushort4*)(out + i * 4) = o;
    }
}

// ---------------- convert + transpose: in [H][F] fp32 -> out [F][H] bf16 ----
__global__ void cvt_tr(const float* __restrict__ in,
                       unsigned short* __restrict__ out) {
    __shared__ float tile[64][65];
    int bh = blockIdx.x & 63;   // H/64 = 64
    int bf = blockIdx.x >> 6;   // F/64 = 224
    int t = threadIdx.x;
    int r16 = t >> 4;           // 0..15
    int c4 = (t & 15) * 4;      // 0..60
#pragma unroll
    for (int it = 0; it < 4; ++it) {
        int h = r16 + it * 16;
        float4 v = *(const float4*)(in + (size_t)(bh * 64 + h) * FF + bf * 64 + c4);
        tile[h][c4 + 0] = v.x; tile[h][c4 + 1] = v.y;
        tile[h][c4 + 2] = v.z; tile[h][c4 + 3] = v.w;
    }
    __syncthreads();
#pragma unroll
    for (int it = 0; it < 4; ++it) {
        int f = r16 + it * 16;
        ushort4 o;
        o.x = f32_to_bf16(tile[c4 + 0][f]);
        o.y = f32_to_bf16(tile[c4 + 1][f]);
        o.z = f32_to_bf16(tile[c4 + 2][f]);
        o.w = f32_to_bf16(tile[c4 + 3][f]);
        *(ushort4*)(out + (size_t)(bf * 64 + f) * HH + bh * 64 + c4) = o;
    }
}

// ---------------- GEMM1: G = Xb@W1b^T, U = Xb@V1b^T, Act = silu(G)*U --------
// Xb [T][H] bf16, W1b/V1b [F][H] bf16 (N-major, K contiguous), Act [T][F] bf16
__global__ __launch_bounds__(256) void gemm_gate_up(
    const unsigned short* __restrict__ Xb,
    const unsigned short* __restrict__ W1b,
    const unsigned short* __restrict__ V1b,
    unsigned short* __restrict__ Act) {
    __shared__ unsigned short lA[128 * 32];
    __shared__ unsigned short lB1[128 * 32];
    __shared__ unsigned short lB2[128 * 32];

    const int NT = FF / 128;  // 112
    int bid = blockIdx.x;
    int tm = bid / NT, tn = bid % NT;
    const int m0 = tm * 128, n0 = tn * 128;

    const int tid = threadIdx.x;
    const int lane = tid & 63;
    const int wave = tid >> 6;
    const int wm = (wave >> 1) * 64;
    const int wn = (wave & 1) * 64;

    f32x4 accg[4][4] = {};
    f32x4 accu[4][4] = {};

    // staging slots: slot s covers row s>>2, cols ((s&3)*8 .. +8) of a 128x32 tile
    const int s0 = tid, s1 = tid + 256;
    const int r0 = s0 >> 2, c0 = (s0 & 3) * 8;
    const int r1 = s1 >> 2, c1 = (s1 & 3) * 8;

    const unsigned short* gA0 = Xb + (size_t)(m0 + r0) * HH + c0;
    const unsigned short* gA1 = Xb + (size_t)(m0 + r1) * HH + c1;
    const unsigned short* gB10 = W1b + (size_t)(n0 + r0) * HH + c0;
    const unsigned short* gB11 = W1b + (size_t)(n0 + r1) * HH + c1;
    const unsigned short* gB20 = V1b + (size_t)(n0 + r0) * HH + c0;
    const unsigned short* gB21 = V1b + (size_t)(n0 + r1) * HH + c1;

    const int fr = lane & 15;
    const int kg = (lane >> 4) * 8;

    for (int k0 = 0; k0 < HH; k0 += 32) {
        GLOAD16(gA0 + k0, lA + s0 * 8);
        GLOAD16(gA1 + k0, lA + s1 * 8);
        GLOAD16(gB10 + k0, lB1 + s0 * 8);
        GLOAD16(gB11 + k0, lB1 + s1 * 8);
        GLOAD16(gB20 + k0, lB2 + s0 * 8);
        GLOAD16(gB21 + k0, lB2 + s1 * 8);
        asm volatile("s_waitcnt vmcnt(0)" ::: "memory");
        __syncthreads();

        bf16x8 a[4], b1[4], b2[4];
#pragma unroll
        for (int i = 0; i < 4; ++i) {
            a[i]  = *(const bf16x8*)(lA  + (wm + i * 16 + fr) * 32 + kg);
            b1[i] = *(const bf16x8*)(lB1 + (wn + i * 16 + fr) * 32 + kg);
            b2[i] = *(const bf16x8*)(lB2 + (wn + i * 16 + fr) * 32 + kg);
        }
#pragma unroll
        for (int i = 0; i < 4; ++i)
#pragma unroll
            for (int j = 0; j < 4; ++j) {
                accg[i][j] = __builtin_amdgcn_mfma_f32_16x16x32_bf16(a[i], b1[j], accg[i][j], 0, 0, 0);
                accu[i][j] = __builtin_amdgcn_mfma_f32_16x16x32_bf16(a[i], b2[j], accu[i][j], 0, 0, 0);
            }
        __syncthreads();
    }

    // epilogue: D mapping n = lane&15, m = (lane>>4)*4 + reg
    const int dn = lane & 15;
    const int dm = (lane >> 4) * 4;
#pragma unroll
    for (int i = 0; i < 4; ++i)
#pragma unroll
        for (int j = 0; j < 4; ++j) {
            size_t base = (size_t)(m0 + wm + i * 16 + dm) * FF + (n0 + wn + j * 16 + dn);
#pragma unroll
            for (int r = 0; r < 4; ++r) {
                float g = accg[i][j][r];
                float u = accu[i][j][r];
                float s = g * u / (1.0f + __expf(-g));
                Act[base + (size_t)r * FF] = f32_to_bf16(s);
            }
        }
}

// ---------------- GEMM2: Out = Act @ W2b^T ----------------------------------
// Act [T][F] bf16, W2b [H][F] bf16 (N-major, K contiguous), Out [T][H] fp32
__global__ __launch_bounds__(256) void gemm_down(
    const unsigned short* __restrict__ Act,
    const unsigned short* __restrict__ W2b,
    float* __restrict__ Out) {
    __shared__ unsigned short lA[128 * 32];
    __shared__ unsigned short lB[128 * 32];

    const int NT = HH / 128;  // 32
    int bid = blockIdx.x;
    int tm = bid / NT, tn = bid % NT;
    const int m0 = tm * 128, n0 = tn * 128;

    const int tid = threadIdx.x;
    const int lane = tid & 63;
    const int wave = tid >> 6;
    const int wm = (wave >> 1) * 64;
    const int wn = (wave & 1) * 64;

    f32x4 acc[4][4] = {};

    const int s0 = tid, s1 = tid + 256;
    const int r0 = s0 >> 2, c0 = (s0 & 3) * 8;
    const int r1 = s1 >> 2, c1 = (s1 & 3) * 8;

    const unsigned short* gA0 = Act + (size_t)(m0 + r0) * FF + c0;
    const unsigned short* gA1 = Act + (size_t)(m0 + r1) * FF + c1;
    const unsigned short* gB0 = W2b + (size_t)(n0 + r0) * FF + c0;
    const unsigned short* gB1 = W2b + (size_t)(n0 + r1) * FF + c1;

    const int fr = lane & 15;
    const int kg = (lane >> 4) * 8;

    for (int k0 = 0; k0 < FF; k0 += 32) {
        GLOAD16(gA0 + k0, lA + s0 * 8);
        GLOAD16(gA1 + k0, lA + s1 * 8);
        GLOAD16(gB0 + k0, lB + s0 * 8);
        GLOAD16(gB1 + k0, lB + s1 * 8);
        asm volatile("s_waitcnt vmcnt(0)" ::: "memory");
        __syncthreads();

        bf16x8 a[4], b[4];
#pragma unroll
        for (int i = 0; i < 4; ++i) {
            a[i] = *(const bf16x8*)(lA + (wm + i * 16 + fr) * 32 + kg);
            b[i] = *(const bf16x8*)(lB + (wn + i * 16 + fr) * 32 + kg);
        }
#pragma unroll
        for (int i = 0; i < 4; ++i)
#pragma unroll
            for (int j = 0; j < 4; ++j)
                acc[i][j] = __builtin_amdgcn_mfma_f32_16x16x32_bf16(a[i], b[j], acc[i][j], 0, 0, 0);
        __syncthreads();
    }

    const int dn = lane & 15;
    const int dm = (lane >> 4) * 4;
#pragma unroll
    for (int i = 0; i < 4; ++i)
#pragma unroll
        for (int j = 0; j < 4; ++j) {
            size_t base = (size_t)(m0 + wm + i * 16 + dm) * HH + (n0 + wn + j * 16 + dn);
#pragma unroll
            for (int r = 0; r < 4; ++r)
                Out[base + (size_t)r * HH] = acc[i][j][r];
        }
}

extern "C" void kernel_launch(void* const* d_in, const int* in_sizes, int n_in,
                              void* d_out, int out_size, void* d_ws, size_t ws_size,
                              hipStream_t stream) {
    const float* x  = (const float*)d_in[0];
    const float* w1 = (const float*)d_in[1];
    const float* v1 = (const float*)d_in[2];
    const float* w2 = (const float*)d_in[3];
    float* out = (float*)d_out;

    unsigned short* xb  = (unsigned short*)d_ws;               // [T][H]
    unsigned short* w1b = xb + (size_t)TT * HH;                // [F][H]
    unsigned short* v1b = w1b + (size_t)FF * HH;               // [F][H]
    unsigned short* w2b = v1b + (size_t)FF * HH;               // [H][F]
    unsigned short* act = w2b + (size_t)HH * FF;               // [T][F]

    cvt_lin<<<2048, 256, 0, stream>>>(x, xb, (long)TT * HH / 4);
    cvt_lin<<<2048, 256, 0, stream>>>(w2, w2b, (long)HH * FF / 4);
    cvt_tr<<<(HH / 64) * (FF / 64), 256, 0, stream>>>(w1, w1b);
    cvt_tr<<<(HH / 64) * (FF / 64), 256, 0, stream>>>(v1, v1b);

    gemm_gate_up<<<(TT / 128) * (FF / 128), 256, 0, stream>>>(xb, w1b, v1b, act);
    gemm_down<<<(TT / 128) * (HH / 128), 256, 0, stream>>>(act, w2b, out);
}

// Round 2
// 2227.295 us; speedup vs baseline: 1.2345x; 1.2345x over previous
//
#include <hip/hip_runtime.h>
#include <hip/hip_bf16.h>
#include <stdint.h>

#define TT 4096
#define HH 4096
#define FF 14336
#define NCAT (2 * FF)   // 28672

typedef __attribute__((ext_vector_type(8))) short bf16x8;
typedef __attribute__((ext_vector_type(4))) float f32x4;

__device__ __forceinline__ unsigned short f32_to_bf16(float f) {
    union { float f; unsigned int u; } v; v.f = f;
    unsigned int r = v.u + 0x7FFFu + ((v.u >> 16) & 1u);  // RNE
    return (unsigned short)(r >> 16);
}

#define GLOAD16(g, l)                                                          \
    __builtin_amdgcn_global_load_lds(                                          \
        (const __attribute__((address_space(1))) void*)(g),                    \
        (__attribute__((address_space(3))) void*)(l), 16, 0, 0)

// ---------------- convert fp32 -> bf16, same layout ----------------
__global__ void cvt_lin(const float* __restrict__ in,
                        unsigned short* __restrict__ out, long n4) {
    long stride = (long)gridDim.x * blockDim.x;
    for (long i = (long)blockIdx.x * blockDim.x + threadIdx.x; i < n4; i += stride) {
        float4 v = *(const float4*)(in + i * 4);
        ushort4 o;
        o.x = f32_to_bf16(v.x); o.y = f32_to_bf16(v.y);
        o.z = f32_to_bf16(v.z); o.w = f32_to_bf16(v.w);
        *(ushort4*)(out + i * 4) = o;
    }
}

// ---- convert + transpose + interleave: in [H][F] fp32 -> wcat rows bf16 ----
// f-column f of `in` goes to wcat row ((f>>4)<<5) + (f&15) + off   (off=0 gate, 16 up)
__global__ void cvt_tri(const float* __restrict__ in,
                        unsigned short* __restrict__ out, int off) {
    __shared__ float tile[64][65];
    int bh = blockIdx.x & 63;   // H/64 = 64
    int bf = blockIdx.x >> 6;   // F/64 = 224
    int t = threadIdx.x;
    int r16 = t >> 4;           // 0..15
    int c4 = (t & 15) * 4;      // 0..60
#pragma unroll
    for (int it = 0; it < 4; ++it) {
        int h = r16 + it * 16;
        float4 v = *(const float4*)(in + (size_t)(bh * 64 + h) * FF + bf * 64 + c4);
        tile[h][c4 + 0] = v.x; tile[h][c4 + 1] = v.y;
        tile[h][c4 + 2] = v.z; tile[h][c4 + 3] = v.w;
    }
    __syncthreads();
#pragma unroll
    for (int it = 0; it < 4; ++it) {
        int f = r16 + it * 16;
        int fg = bf * 64 + f;
        int row_out = ((fg >> 4) << 5) + (fg & 15) + off;
        ushort4 o;
        o.x = f32_to_bf16(tile[c4 + 0][f]);
        o.y = f32_to_bf16(tile[c4 + 1][f]);
        o.z = f32_to_bf16(tile[c4 + 2][f]);
        o.w = f32_to_bf16(tile[c4 + 3][f]);
        *(ushort4*)(out + (size_t)row_out * HH + bh * 64 + c4) = o;
    }
}

// ---------------- GEMM1: acc = Xb @ Wcat^T, fused SwiGLU epilogue ----------
// Xb [T][H] bf16, Wcat [2F][H] bf16 (16-col interleaved gate/up), Act [T][F] bf16
__global__ __launch_bounds__(256) void gemm_swiglu(
    const unsigned short* __restrict__ Xb,
    const unsigned short* __restrict__ Wcat,
    unsigned short* __restrict__ Act) {
    __shared__ unsigned short lA[128 * 32];
    __shared__ unsigned short lB[128 * 32];

    const int MT = TT / 128;    // 32
    const int NWG = MT * (NCAT / 128);  // 7168
    int log_id = (blockIdx.x & 7) * (NWG / 8) + (blockIdx.x >> 3);  // XCD chunk swizzle
    int tm = log_id & 31;       // tm fast: weight panels stream once
    int tn = log_id >> 5;
    const int m0 = tm * 128, n0 = tn * 128;

    const int tid = threadIdx.x;
    const int lane = tid & 63;
    const int wave = tid >> 6;
    const int wm = (wave >> 1) * 64;
    const int wn = (wave & 1) * 64;

    f32x4 acc[4][4] = {};

    const int s0 = tid, s1 = tid + 256;
    const int r0 = s0 >> 2, c0 = (s0 & 3) * 8;
    const int r1 = s1 >> 2, c1 = (s1 & 3) * 8;

    const unsigned short* gA0 = Xb + (size_t)(m0 + r0) * HH + c0;
    const unsigned short* gA1 = Xb + (size_t)(m0 + r1) * HH + c1;
    const unsigned short* gB0 = Wcat + (size_t)(n0 + r0) * HH + c0;
    const unsigned short* gB1 = Wcat + (size_t)(n0 + r1) * HH + c1;

    const int fr = lane & 15;
    const int kg = (lane >> 4) * 8;

    for (int k0 = 0; k0 < HH; k0 += 32) {
        GLOAD16(gA0 + k0, lA + s0 * 8);
        GLOAD16(gA1 + k0, lA + s1 * 8);
        GLOAD16(gB0 + k0, lB + s0 * 8);
        GLOAD16(gB1 + k0, lB + s1 * 8);
        asm volatile("s_waitcnt vmcnt(0)" ::: "memory");
        __syncthreads();

        bf16x8 a[4], b[4];
#pragma unroll
        for (int i = 0; i < 4; ++i) {
            a[i] = *(const bf16x8*)(lA + (wm + i * 16 + fr) * 32 + kg);
            b[i] = *(const bf16x8*)(lB + (wn + i * 16 + fr) * 32 + kg);
        }
#pragma unroll
        for (int i = 0; i < 4; ++i)
#pragma unroll
            for (int j = 0; j < 4; ++j)
                acc[i][j] = __builtin_amdgcn_mfma_f32_16x16x32_bf16(a[i], b[j], acc[i][j], 0, 0, 0);
        __syncthreads();
    }

    // epilogue: frag j even = gate, j odd = up, same 16 act-columns.
    // act col = (n0+wn)/2 + (j/2)*16 + dn ; row = m0+wm+i*16+(lane>>4)*4+r
    const int dn = lane & 15;
    const int dm = (lane >> 4) * 4;
    const int acol0 = (n0 + wn) / 2;
#pragma unroll
    for (int i = 0; i < 4; ++i)
#pragma unroll
        for (int jp = 0; jp < 2; ++jp) {
            f32x4 g4 = acc[i][2 * jp];
            f32x4 u4 = acc[i][2 * jp + 1];
            size_t base = (size_t)(m0 + wm + i * 16 + dm) * FF + (acol0 + jp * 16 + dn);
#pragma unroll
            for (int r = 0; r < 4; ++r) {
                float g = g4[r], u = u4[r];
                float s = g * u / (1.0f + __expf(-g));
                Act[base + (size_t)r * FF] = f32_to_bf16(s);
            }
        }
}

// ---------------- GEMM2: Out = Act @ W2b^T ----------------------------------
// Act [T][F] bf16, W2b [H][F] bf16 (N-major, K contiguous), Out [T][H] fp32
__global__ __launch_bounds__(256) void gemm_down(
    const unsigned short* __restrict__ Act,
    const unsigned short* __restrict__ W2b,
    float* __restrict__ Out) {
    __shared__ unsigned short lA[128 * 32];
    __shared__ unsigned short lB[128 * 32];

    const int NWG = (TT / 128) * (HH / 128);  // 1024
    int log_id = (blockIdx.x & 7) * (NWG / 8) + (blockIdx.x >> 3);
    int tm = log_id & 31;
    int tn = log_id >> 5;
    const int m0 = tm * 128, n0 = tn * 128;

    const int tid = threadIdx.x;
    const int lane = tid & 63;
    const int wave = tid >> 6;
    const int wm = (wave >> 1) * 64;
    const int wn = (wave & 1) * 64;

    f32x4 acc[4][4] = {};

    const int s0 = tid, s1 = tid + 256;
    const int r0 = s0 >> 2, c0 = (s0 & 3) * 8;
    const int r1 = s1 >> 2, c1 = (s1 & 3) * 8;

    const unsigned short* gA0 = Act + (size_t)(m0 + r0) * FF + c0;
    const unsigned short* gA1 = Act + (size_t)(m0 + r1) * FF + c1;
    const unsigned short* gB0 = W2b + (size_t)(n0 + r0) * FF + c0;
    const unsigned short* gB1 = W2b + (size_t)(n0 + r1) * FF + c1;

    const int fr = lane & 15;
    const int kg = (lane >> 4) * 8;

    for (int k0 = 0; k0 < FF; k0 += 32) {
        GLOAD16(gA0 + k0, lA + s0 * 8);
        GLOAD16(gA1 + k0, lA + s1 * 8);
        GLOAD16(gB0 + k0, lB + s0 * 8);
        GLOAD16(gB1 + k0, lB + s1 * 8);
        asm volatile("s_waitcnt vmcnt(0)" ::: "memory");
        __syncthreads();

        bf16x8 a[4], b[4];
#pragma unroll
        for (int i = 0; i < 4; ++i) {
            a[i] = *(const bf16x8*)(lA + (wm + i * 16 + fr) * 32 + kg);
            b[i] = *(const bf16x8*)(lB + (wn + i * 16 + fr) * 32 + kg);
        }
#pragma unroll
        for (int i = 0; i < 4; ++i)
#pragma unroll
            for (int j = 0; j < 4; ++j)
                acc[i][j] = __builtin_amdgcn_mfma_f32_16x16x32_bf16(a[i], b[j], acc[i][j], 0, 0, 0);
        __syncthreads();
    }

    const int dn = lane & 15;
    const int dm = (lane >> 4) * 4;
#pragma unroll
    for (int i = 0; i < 4; ++i)
#pragma unroll
        for (int j = 0; j < 4; ++j) {
            size_t base = (size_t)(m0 + wm + i * 16 + dm) * HH + (n0 + wn + j * 16 + dn);
#pragma unroll
            for (int r = 0; r < 4; ++r)
                Out[base + (size_t)r * HH] = acc[i][j][r];
        }
}

extern "C" void kernel_launch(void* const* d_in, const int* in_sizes, int n_in,
                              void* d_out, int out_size, void* d_ws, size_t ws_size,
                              hipStream_t stream) {
    const float* x  = (const float*)d_in[0];
    const float* w1 = (const float*)d_in[1];
    const float* v1 = (const float*)d_in[2];
    const float* w2 = (const float*)d_in[3];
    float* out = (float*)d_out;

    unsigned short* xb   = (unsigned short*)d_ws;               // [T][H]     64 MB
    unsigned short* wcat = xb + (size_t)TT * HH;                // [2F][H]   235 MB
    unsigned short* w2b  = wcat + (size_t)NCAT * HH;            // [H][F]    117 MB
    unsigned short* act  = w2b + (size_t)HH * FF;               // [T][F]    117 MB

    cvt_lin<<<2048, 256, 0, stream>>>(x, xb, (long)TT * HH / 4);
    cvt_lin<<<2048, 256, 0, stream>>>(w2, w2b, (long)HH * FF / 4);
    cvt_tri<<<(HH / 64) * (FF / 64), 256, 0, stream>>>(w1, wcat, 0);
    cvt_tri<<<(HH / 64) * (FF / 64), 256, 0, stream>>>(v1, wcat, 16);

    gemm_swiglu<<<(TT / 128) * (NCAT / 128), 256, 0, stream>>>(xb, wcat, act);
    gemm_down<<<(TT / 128) * (HH / 128), 256, 0, stream>>>(act, w2b, out);
}

// Round 3
// 1473.204 us; speedup vs baseline: 1.8664x; 1.5119x over previous
//
#include <hip/hip_runtime.h>
#include <hip/hip_bf16.h>
#include <stdint.h>

#define TT 4096
#define HH 4096
#define FF 14336
#define NCAT (2 * FF)   // 28672

typedef __attribute__((ext_vector_type(8))) short bf16x8;
typedef __attribute__((ext_vector_type(4))) float f32x4;

__device__ __forceinline__ unsigned short f32_to_bf16(float f) {
    union { float f; unsigned int u; } v; v.f = f;
    unsigned int r = v.u + 0x7FFFu + ((v.u >> 16) & 1u);  // RNE
    return (unsigned short)(r >> 16);
}

#define GLOAD16(g, l)                                                          \
    __builtin_amdgcn_global_load_lds(                                          \
        (const __attribute__((address_space(1))) void*)(g),                    \
        (__attribute__((address_space(3))) void*)(l), 16, 0, 0)

// ---------------- convert fp32 -> bf16, same layout ----------------
__global__ void cvt_lin(const float* __restrict__ in,
                        unsigned short* __restrict__ out, long n4) {
    long stride = (long)gridDim.x * blockDim.x;
    for (long i = (long)blockIdx.x * blockDim.x + threadIdx.x; i < n4; i += stride) {
        float4 v = *(const float4*)(in + i * 4);
        ushort4 o;
        o.x = f32_to_bf16(v.x); o.y = f32_to_bf16(v.y);
        o.z = f32_to_bf16(v.z); o.w = f32_to_bf16(v.w);
        *(ushort4*)(out + i * 4) = o;
    }
}

// ---- convert + transpose + interleave: in [H][F] fp32 -> wcat rows bf16 ----
// f-column f of `in` goes to wcat row ((f>>4)<<5) + (f&15) + off   (off=0 gate, 16 up)
__global__ void cvt_tri(const float* __restrict__ in,
                        unsigned short* __restrict__ out, int off) {
    __shared__ float tile[64][65];
    int bh = blockIdx.x & 63;   // H/64 = 64
    int bf = blockIdx.x >> 6;   // F/64 = 224
    int t = threadIdx.x;
    int r16 = t >> 4;           // 0..15
    int c4 = (t & 15) * 4;      // 0..60
#pragma unroll
    for (int it = 0; it < 4; ++it) {
        int h = r16 + it * 16;
        float4 v = *(const float4*)(in + (size_t)(bh * 64 + h) * FF + bf * 64 + c4);
        tile[h][c4 + 0] = v.x; tile[h][c4 + 1] = v.y;
        tile[h][c4 + 2] = v.z; tile[h][c4 + 3] = v.w;
    }
    __syncthreads();
#pragma unroll
    for (int it = 0; it < 4; ++it) {
        int f = r16 + it * 16;
        int fg = bf * 64 + f;
        int row_out = ((fg >> 4) << 5) + (fg & 15) + off;
        ushort4 o;
        o.x = f32_to_bf16(tile[c4 + 0][f]);
        o.y = f32_to_bf16(tile[c4 + 1][f]);
        o.z = f32_to_bf16(tile[c4 + 2][f]);
        o.w = f32_to_bf16(tile[c4 + 3][f]);
        *(ushort4*)(out + (size_t)row_out * HH + bh * 64 + c4) = o;
    }
}

// =================== 8-phase 256x256 GEMM core (BK=64, 8 waves) ============
// LDS: lsA[2buf][2mhalf][128][64]b16 (16KiB slots), lsB same. 128 KiB total.
// Swizzle: byte ^= ((row&6)<<4)  (involution; applied to gload SOURCE and ds_read).

#define STG_A(BUF, SLOT, TILE) do {                                            \
    char* d_ = lsA + (((BUF)*2 + (SLOT)) << 14) + tid * 16;                    \
    GLOAD16(sA[SLOT][0] + (size_t)(TILE) * 64, d_);                            \
    GLOAD16(sA[SLOT][1] + (size_t)(TILE) * 64, d_ + 8192);                     \
  } while (0)

#define STG_B(BUF, SLOT, TILE) do {                                            \
    char* d_ = lsB + (((BUF)*2 + (SLOT)) << 14) + tid * 16;                    \
    GLOAD16(sB[SLOT][0] + (size_t)(TILE) * 64, d_);                            \
    GLOAD16(sB[SLOT][1] + (size_t)(TILE) * 64, d_ + 8192);                     \
  } while (0)

#define PHASE(BUF, MQ, NQ, STAGES, FENCE) do {                                 \
    const char* pA_ = lsA + (((BUF)*2 + (MQ)) << 14);                          \
    const char* pB_ = lsB + (((BUF)*2 + (NQ)) << 14);                          \
    bf16x8 af_[4][2], bf_[2][2];                                               \
    _Pragma("unroll") for (int i_ = 0; i_ < 4; ++i_)                           \
    _Pragma("unroll") for (int k_ = 0; k_ < 2; ++k_)                           \
      af_[i_][k_] = *(const bf16x8*)(pA_ + ((((wr*64 + i_*16 + fr) << 7) + k_*64 + kg2) ^ lmask)); \
    _Pragma("unroll") for (int j_ = 0; j_ < 2; ++j_)                           \
    _Pragma("unroll") for (int k_ = 0; k_ < 2; ++k_)                           \
      bf_[j_][k_] = *(const bf16x8*)(pB_ + ((((wc*32 + j_*16 + fr) << 7) + k_*64 + kg2) ^ lmask)); \
    STAGES;                                                                    \
    asm volatile("" ::: "memory");                                             \
    __builtin_amdgcn_s_barrier();                                              \
    asm volatile("" ::: "memory");                                             \
    __builtin_amdgcn_s_setprio(1);                                             \
    _Pragma("unroll") for (int i_ = 0; i_ < 4; ++i_)                           \
    _Pragma("unroll") for (int j_ = 0; j_ < 2; ++j_)                           \
    _Pragma("unroll") for (int k_ = 0; k_ < 2; ++k_)                           \
      acc[MQ][i_][NQ][j_] = __builtin_amdgcn_mfma_f32_16x16x32_bf16(           \
          af_[i_][k_], bf_[j_][k_], acc[MQ][i_][NQ][j_], 0, 0, 0);             \
    __builtin_amdgcn_s_setprio(0);                                             \
    FENCE;                                                                     \
    asm volatile("" ::: "memory");                                             \
    __builtin_amdgcn_s_barrier();                                              \
    asm volatile("" ::: "memory");                                             \
  } while (0)

#define VMC4 asm volatile("s_waitcnt vmcnt(4)" ::: "memory")
#define VMC0 asm volatile("s_waitcnt vmcnt(0)" ::: "memory")

#define GEMM8_CORE(A_, LDA_, B_, LDB_, NT_)                                    \
  extern __shared__ char smem[];                                               \
  char* const lsA = smem;                                                      \
  char* const lsB = smem + 65536;                                              \
  const int tid = threadIdx.x;                                                 \
  const int lane = tid & 63;                                                   \
  const int wid = tid >> 6;                                                    \
  const int wr = wid >> 2;                                                     \
  const int wc = wid & 3;                                                      \
  const int fr = lane & 15;                                                    \
  const int kg2 = ((lane >> 4) & 3) << 4;                                      \
  const int lmask = (fr & 6) << 4;                                             \
  f32x4 acc[2][4][2][2];                                                       \
  _Pragma("unroll") for (int a_ = 0; a_ < 2; ++a_)                             \
  _Pragma("unroll") for (int b_ = 0; b_ < 4; ++b_)                             \
  _Pragma("unroll") for (int c_ = 0; c_ < 2; ++c_)                             \
  _Pragma("unroll") for (int d_ = 0; d_ < 2; ++d_)                             \
    acc[a_][b_][c_][d_] = (f32x4){0.f, 0.f, 0.f, 0.f};                         \
  const unsigned short* sA[2][2];                                              \
  const unsigned short* sB[2][2];                                              \
  _Pragma("unroll") for (int c_ = 0; c_ < 2; ++c_) {                           \
    int d_ = (tid + 512 * c_) * 16;                                            \
    int p_ = d_ ^ (((d_ >> 8) & 3) << 5);                                      \
    int prow = p_ >> 7, pcol = (p_ & 127) >> 1;                                \
    _Pragma("unroll") for (int s_ = 0; s_ < 2; ++s_) {                         \
      int grA = m0 + ((prow >> 6) & 1) * 128 + s_ * 64 + (prow & 63);          \
      sA[s_][c_] = (A_) + (size_t)grA * (LDA_) + pcol;                         \
      int grB = n0 + (prow >> 5) * 64 + s_ * 32 + (prow & 31);                 \
      sB[s_][c_] = (B_) + (size_t)grB * (LDB_) + pcol;                         \
    }                                                                          \
  }                                                                            \
  /* prologue: tile0 fully + tile1.{A0,B0}; allow last 2 half-tiles in flight */\
  STG_A(0, 0, 0); STG_B(0, 0, 0); STG_B(0, 1, 0); STG_A(0, 1, 0);              \
  STG_A(1, 0, 1); STG_B(1, 0, 1);                                              \
  VMC4;                                                                        \
  __builtin_amdgcn_s_barrier();                                                \
  asm volatile("" ::: "memory");                                               \
  const int niter = (NT_) / 2;                                                 \
  for (int I = 0; I < niter - 1; ++I) {                                        \
    const int t = 2 * I;                                                       \
    PHASE(0, 0, 0, STG_B(1, 1, t + 1), );                                      \
    PHASE(0, 0, 1, STG_A(1, 1, t + 1), );                                      \
    PHASE(0, 1, 0, STG_A(0, 0, t + 2), );                                      \
    PHASE(0, 1, 1, STG_B(0, 0, t + 2), VMC4);                                  \
    PHASE(1, 0, 0, STG_B(0, 1, t + 2), );                                      \
    PHASE(1, 0, 1, STG_A(0, 1, t + 2), );                                      \
    PHASE(1, 1, 0, STG_A(1, 0, t + 3), );                                      \
    PHASE(1, 1, 1, STG_B(1, 0, t + 3), VMC4);                                  \
  }                                                                            \
  {                                                                            \
    const int t = (NT_) - 2;                                                   \
    PHASE(0, 0, 0, STG_B(1, 1, t + 1), );                                      \
    PHASE(0, 0, 1, STG_A(1, 1, t + 1), );                                      \
    PHASE(0, 1, 0, , );                                                        \
    PHASE(0, 1, 1, , VMC0);                                                    \
    PHASE(1, 0, 0, , );                                                        \
    PHASE(1, 0, 1, , );                                                        \
    PHASE(1, 1, 0, , );                                                        \
    PHASE(1, 1, 1, , );                                                        \
  }

// ---------------- GEMM1: acc = Xb @ Wcat^T, fused SwiGLU epilogue ----------
__global__ __launch_bounds__(512, 2) void gemm_swiglu(
    const unsigned short* __restrict__ Xb,
    const unsigned short* __restrict__ Wcat,
    unsigned short* __restrict__ Act) {
    const int NWG = (TT / 256) * (NCAT / 256);  // 16*112 = 1792
    int lid = (blockIdx.x & 7) * (NWG / 8) + (blockIdx.x >> 3);
    const int m0 = (lid & 15) * 256;   // tm fast: weight panel reused across XCD chunk
    const int n0 = (lid >> 4) * 256;

    GEMM8_CORE(Xb, HH, Wcat, HH, HH / 64)

    const int dm = ((lane >> 4) & 3) * 4;
    const int dn = lane & 15;
#pragma unroll
    for (int mq = 0; mq < 2; ++mq)
#pragma unroll
        for (int i = 0; i < 4; ++i)
#pragma unroll
            for (int nq = 0; nq < 2; ++nq) {
                int rowb = m0 + wr * 128 + mq * 64 + i * 16 + dm;
                int col = (n0 + wc * 64 + nq * 32) / 2 + dn;
                f32x4 g4 = acc[mq][i][nq][0];
                f32x4 u4 = acc[mq][i][nq][1];
#pragma unroll
                for (int r = 0; r < 4; ++r) {
                    float g = g4[r], u = u4[r];
                    float s = g * u / (1.0f + __expf(-g));
                    Act[(size_t)(rowb + r) * FF + col] = f32_to_bf16(s);
                }
            }
}

// ---------------- GEMM2: Out = Act @ W2b^T ----------------------------------
__global__ __launch_bounds__(512, 2) void gemm_down(
    const unsigned short* __restrict__ Act,
    const unsigned short* __restrict__ W2b,
    float* __restrict__ Out) {
    const int NWG = (TT / 256) * (HH / 256);  // 16*16 = 256
    int lid = (blockIdx.x & 7) * (NWG / 8) + (blockIdx.x >> 3);
    const int m0 = (lid & 15) * 256;
    const int n0 = (lid >> 4) * 256;

    GEMM8_CORE(Act, FF, W2b, FF, FF / 64)

    const int dm = ((lane >> 4) & 3) * 4;
    const int dn = lane & 15;
#pragma unroll
    for (int mq = 0; mq < 2; ++mq)
#pragma unroll
        for (int i = 0; i < 4; ++i)
#pragma unroll
            for (int nq = 0; nq < 2; ++nq)
#pragma unroll
                for (int j = 0; j < 2; ++j) {
                    int rowb = m0 + wr * 128 + mq * 64 + i * 16 + dm;
                    int col = n0 + wc * 64 + nq * 32 + j * 16 + dn;
                    f32x4 v = acc[mq][i][nq][j];
#pragma unroll
                    for (int r = 0; r < 4; ++r)
                        Out[(size_t)(rowb + r) * HH + col] = v[r];
                }
}

extern "C" void kernel_launch(void* const* d_in, const int* in_sizes, int n_in,
                              void* d_out, int out_size, void* d_ws, size_t ws_size,
                              hipStream_t stream) {
    const float* x  = (const float*)d_in[0];
    const float* w1 = (const float*)d_in[1];
    const float* v1 = (const float*)d_in[2];
    const float* w2 = (const float*)d_in[3];
    float* out = (float*)d_out;

    unsigned short* xb   = (unsigned short*)d_ws;               // [T][H]
    unsigned short* wcat = xb + (size_t)TT * HH;                // [2F][H]
    unsigned short* w2b  = wcat + (size_t)NCAT * HH;            // [H][F]
    unsigned short* act  = w2b + (size_t)HH * FF;               // [T][F]

    hipFuncSetAttribute((const void*)gemm_swiglu,
                        hipFuncAttributeMaxDynamicSharedMemorySize, 131072);
    hipFuncSetAttribute((const void*)gemm_down,
                        hipFuncAttributeMaxDynamicSharedMemorySize, 131072);

    cvt_lin<<<2048, 256, 0, stream>>>(x, xb, (long)TT * HH / 4);
    cvt_lin<<<2048, 256, 0, stream>>>(w2, w2b, (long)HH * FF / 4);
    cvt_tri<<<(HH / 64) * (FF / 64), 256, 0, stream>>>(w1, wcat, 0);
    cvt_tri<<<(HH / 64) * (FF / 64), 256, 0, stream>>>(v1, wcat, 16);

    gemm_swiglu<<<(TT / 256) * (NCAT / 256), 512, 131072, stream>>>(xb, wcat, act);
    gemm_down<<<(TT / 256) * (HH / 256), 512, 131072, stream>>>(act, w2b, out);
}